// Round 8
// baseline (357.014 us; speedup 1.0000x reference)
//
#include <hip/hip_runtime.h>
#include <hip/hip_bf16.h>

// ---------------------------------------------------------------------------
// MoE dense all-expert forward, MI355X / gfx950.  B=16384, D=H=O=256, E=32.
// Round 8 = round-5 crew design, spill-free by construction:
//  - ONE shared acc[4][8] register array: crew0 treats it as per-expert hacc,
//    crew1 as persistent out accumulator -> single 128-reg allocation, both
//    crews fit the 256-reg/wave cap of a 512-thread block (2 waves/SIMD).
//  - no __launch_bounds__ min-arg (r5's (512,2) forced a 128-VGPR cap+spill)
//  - 128-row x 16-expert blocks (1 GB weight traffic), lgkm-only barriers,
//    distance-2 ping-pong weight prefetch, eg-split for per-XCD L2 locality.
// ---------------------------------------------------------------------------

typedef __attribute__((ext_vector_type(8))) short bf16x8;   // 8 bf16 = 4 VGPRs
typedef __attribute__((ext_vector_type(4))) float f32x4;

__device__ __forceinline__ unsigned short f2bf(float f) {
    unsigned u = __builtin_bit_cast(unsigned, f);
    u += 0x7FFFu + ((u >> 16) & 1u);        // round-to-nearest-even
    return (unsigned short)(u >> 16);
}
__device__ __forceinline__ unsigned pack_bf16x2(float a, float b) {
    return (unsigned)f2bf(a) | ((unsigned)f2bf(b) << 16);
}

// barrier that waits only LDS (lgkmcnt), leaving global prefetches in flight
__device__ __forceinline__ void lds_barrier() {
    asm volatile("s_waitcnt lgkmcnt(0)\n\ts_barrier" ::: "memory");
}

// 16B-chunk XOR swizzle for [rows][256 elem] bf16 tiles (index in ushorts)
#define LX(r, ch) (((r) << 8) + ((((ch) ^ ((r) & 7))) << 3))

// ------------------- W f32 -> bf16 convert + tile reorder ------------------
// chunk c = (e*8 + slot)*8 + kb ; slot 0-3 = W1 rows slot*64.., 4-7 = W2.
// chunk = 2048 bf16 = 4 KB; element (t,lane,j): row = slot64 + t*16 + (lane&15),
// k = kb*32 + (lane>>4)*8 + j  — the mfma_16x16x32 A-frag order.
__global__ __launch_bounds__(256) void cvt_w(const float* __restrict__ W1,
                                             const float* __restrict__ W2,
                                             unsigned short* __restrict__ Wr) {
    int T = blockIdx.x * 256 + threadIdx.x;          // 524288 threads
    int lane = T & 63, t = (T >> 6) & 3, kb = (T >> 8) & 7;
    int g = (T >> 11) & 7, e = T >> 14;
    int l15 = lane & 15, quad = lane >> 4;
    int row = (g & 3) * 64 + t * 16 + l15;
    const float* src = ((g < 4) ? W1 : W2) +
                       ((long)e * 256 + row) * 256 + kb * 32 + quad * 8;
    float4 v0 = ((const float4*)src)[0], v1 = ((const float4*)src)[1];
    uint4 o;
    o.x = pack_bf16x2(v0.x, v0.y); o.y = pack_bf16x2(v0.z, v0.w);
    o.z = pack_bf16x2(v1.x, v1.y); o.w = pack_bf16x2(v1.z, v1.w);
    ((uint4*)Wr)[T] = o;
}

// ------------------------------ fused MoE ----------------------------------
// 256 blocks x 512 thr. Block = (row-group rg of 128 rows) x (expert half eg).
// crew0 (waves 0-3): h(e)^T = W1[e].x^T ; crew1 (waves 4-7): acc += W2[e-1].h^T
__global__ __launch_bounds__(512) void moe_kernel(
    const float* __restrict__ x,
    const unsigned short* __restrict__ Wr,
    const float* __restrict__ bias1,
    const float* __restrict__ b2,
    const float* __restrict__ Wg,
    const float* __restrict__ bg,
    float* __restrict__ out,
    float* __restrict__ part1)
{
    __shared__ __align__(16) unsigned short x_s[128 * 256];  // 64 KB
    __shared__ __align__(16) unsigned short h_s[128 * 256];  // 64 KB
    __shared__ float gws[128 * 17];                          // 8.5 KB

    const int tid  = threadIdx.x;
    const int wv   = tid >> 6, lane = tid & 63;
    const int quad = lane >> 4, l15 = lane & 15;
    const int crew = wv >> 2, g = wv & 3;       // crew0 = GEMM1, crew1 = GEMM2
    const int eg   = blockIdx.x & 1;            // expert half (0..15 / 16..31)
    const int rg   = blockIdx.x >> 1;
    const int row0 = rg * 128;
    const int ebase = eg * 16;

    // ---- stage x tile: f32 global -> bf16 LDS (swizzled) ----
#pragma unroll
    for (int c = 0; c < 8; ++c) {
        int chunk = tid + c * 512;              // 4096 chunks of 8 elems
        int r = chunk >> 5, ch = chunk & 31;
        const float4* s = (const float4*)(x + (long)(row0 + r) * 256 + ch * 8);
        float4 v0 = s[0], v1 = s[1];
        uint4 o;
        o.x = pack_bf16x2(v0.x, v0.y); o.y = pack_bf16x2(v0.z, v0.w);
        o.z = pack_bf16x2(v1.x, v1.y); o.w = pack_bf16x2(v1.z, v1.w);
        *(uint4*)(&x_s[LX(r, ch)]) = o;
    }

    // ---- inline gating: 16 rows per wave, all f32 (matches reference) ----
    {
        const int e32 = lane & 31, half = lane >> 5;
        const float4* wg4 = (const float4*)(Wg + e32 * 256 + half * 128);
        float bgv = bg[e32];
        for (int i = 0; i < 16; ++i) {
            int lr = wv * 16 + i;
            const float4* xr4 = (const float4*)(x + (long)(row0 + lr) * 256 + half * 128);
            float acc0 = 0.f;
#pragma unroll
            for (int tt = 0; tt < 32; ++tt) {
                float4 w = wg4[tt], xv = xr4[tt];
                acc0 = fmaf(w.x, xv.x, acc0); acc0 = fmaf(w.y, xv.y, acc0);
                acc0 = fmaf(w.z, xv.z, acc0); acc0 = fmaf(w.w, xv.w, acc0);
            }
            acc0 += __shfl_xor(acc0, 32);
            float score = (acc0 + bgv) / 2.71828182845904523f;  // TEMP = e

            float m = score;
#pragma unroll
            for (int d = 16; d >= 1; d >>= 1) m = fmaxf(m, __shfl_xor(m, d));
            float p = expf(score - m);
            float ps = p;
#pragma unroll
            for (int d = 16; d >= 1; d >>= 1) ps += __shfl_xor(ps, d);
            float prob = p / ps;

            int rank = 0;
#pragma unroll
            for (int j = 0; j < 32; ++j) {
                float pj = __shfl(prob, j);
                rank += (pj > prob || (pj == prob && j < e32)) ? 1 : 0;
            }
            float kept = (rank < 22) ? prob : 0.f;
            float wsum = kept;
#pragma unroll
            for (int d = 16; d >= 1; d >>= 1) wsum += __shfl_xor(wsum, d);
            float weight = kept / (wsum + 1e-8f);

            if (half == 0 && (e32 >> 4) == eg)
                gws[lr * 17 + (e32 & 15)] = weight;
        }
    }

    lds_barrier();   // x_s + gws ready

    // ---- SHARED accumulator array: crew0 -> per-expert hacc,
    //      crew1 -> persistent out acc (init = sum_{local e} gw*b2) ----
    f32x4 acc[4][8];                            // [mt][rt], ~128 regs, AGPR
    if (crew == 1) {
#pragma unroll
        for (int ot = 0; ot < 4; ++ot)
#pragma unroll
            for (int rt = 0; rt < 8; ++rt) {
                f32x4 z = {0.f, 0.f, 0.f, 0.f};
                acc[ot][rt] = z;
            }
        for (int ee = 0; ee < 16; ++ee) {
            float gv[8];
#pragma unroll
            for (int rt = 0; rt < 8; ++rt) gv[rt] = gws[(rt * 16 + l15) * 17 + ee];
#pragma unroll
            for (int ot = 0; ot < 4; ++ot) {
                float4 bb = *(const float4*)(b2 + (ebase + ee) * 256 + g * 64 + ot * 16 + quad * 4);
#pragma unroll
                for (int rt = 0; rt < 8; ++rt) {
                    acc[ot][rt][0] = fmaf(gv[rt], bb.x, acc[ot][rt][0]);
                    acc[ot][rt][1] = fmaf(gv[rt], bb.y, acc[ot][rt][1]);
                    acc[ot][rt][2] = fmaf(gv[rt], bb.z, acc[ot][rt][2]);
                    acc[ot][rt][3] = fmaf(gv[rt], bb.w, acc[ot][rt][3]);
                }
            }
        }
    }

    // ---- weight stream: per-wave base; expert stride 131072, kb stride 2048 ----
    const unsigned short* wbase = Wr + ((long)ebase * 8 + wv) * 16384;

    // preload chunks (local expert 0, kb 0 and 1) — distance-2 ping-pong
    bf16x8 q0[4], q1[4];
#pragma unroll
    for (int t = 0; t < 4; ++t) q0[t] = *(const bf16x8*)(wbase + t * 512 + lane * 8);
#pragma unroll
    for (int t = 0; t < 4; ++t) q1[t] = *(const bf16x8*)(wbase + 2048 + t * 512 + lane * 8);

    // ---- expert pipeline: crew0 computes e, crew1 computes e-1 ----
#pragma unroll 1
    for (int e = 0; e <= 16; ++e) {
        if (crew == 0) {
            if (e < 16) {
#pragma unroll
                for (int ht = 0; ht < 4; ++ht)
#pragma unroll
                    for (int rt = 0; rt < 8; ++rt) {
                        f32x4 z = {0.f, 0.f, 0.f, 0.f};
                        acc[ht][rt] = z;       // crew0: fresh hacc
                    }
                const unsigned short* wcur = wbase + (long)e * 131072;
#pragma unroll
                for (int kb = 0; kb < 8; ++kb) {
                    bf16x8 bx[8];
#pragma unroll
                    for (int rt = 0; rt < 8; ++rt)
                        bx[rt] = *(const bf16x8*)(&x_s[LX(rt * 16 + l15, kb * 4 + quad)]);
#pragma unroll
                    for (int ht = 0; ht < 4; ++ht)
#pragma unroll
                        for (int rt = 0; rt < 8; ++rt)
                            acc[ht][rt] = __builtin_amdgcn_mfma_f32_16x16x32_bf16(
                                q0[ht], bx[rt], acc[ht][rt], 0, 0, 0);
                    // rotate + prefetch distance 2
#pragma unroll
                    for (int t = 0; t < 4; ++t) q0[t] = q1[t];
                    const unsigned short* pf = (kb < 6)
                        ? (wcur + (kb + 2) * 2048)
                        : (wcur + 131072 + (kb - 6) * 2048);
#pragma unroll
                    for (int t = 0; t < 4; ++t)
                        q1[t] = *(const bf16x8*)(pf + t * 512 + lane * 8);
                }
            }
        } else {
            if (e >= 1) {
                const unsigned short* wcur = wbase + (long)(e - 1) * 131072;
#pragma unroll
                for (int kb = 0; kb < 8; ++kb) {
                    bf16x8 bx[8];
#pragma unroll
                    for (int rt = 0; rt < 8; ++rt)
                        bx[rt] = *(const bf16x8*)(&h_s[LX(rt * 16 + l15, kb * 4 + quad)]);
#pragma unroll
                    for (int ot = 0; ot < 4; ++ot)
#pragma unroll
                        for (int rt = 0; rt < 8; ++rt)
                            acc[ot][rt] = __builtin_amdgcn_mfma_f32_16x16x32_bf16(
                                q0[ot], bx[rt], acc[ot][rt], 0, 0, 0);
#pragma unroll
                    for (int t = 0; t < 4; ++t) q0[t] = q1[t];
                    const unsigned short* pf = (kb < 6)
                        ? (wcur + (kb + 2) * 2048)
                        : (wcur + 131072 + (kb - 6) * 2048);
#pragma unroll
                    for (int t = 0; t < 4; ++t)
                        q1[t] = *(const bf16x8*)(pf + t * 512 + lane * 8);
                }
            }
        }

        lds_barrier();   // crew1 done reading h_s(e-1); crew0 acc(e) ready

        if (crew == 0 && e < 16) {
            // epilogue: +b1, relu, * gate weight, packed b64 -> h_s
            float4 bv[4]; float gw[8];
#pragma unroll
            for (int ht = 0; ht < 4; ++ht)
                bv[ht] = *(const float4*)(bias1 + (ebase + e) * 256 + g * 64 + ht * 16 + quad * 4);
#pragma unroll
            for (int rt = 0; rt < 8; ++rt)
                gw[rt] = gws[(rt * 16 + l15) * 17 + e];
#pragma unroll
            for (int ht = 0; ht < 4; ++ht) {
                int hb = g * 64 + ht * 16 + quad * 4;   // 4 consecutive h-cols
                int ch = hb >> 3, off = hb & 7;
#pragma unroll
                for (int rt = 0; rt < 8; ++rt) {
                    int r = rt * 16 + l15;
                    float v0 = fmaxf(acc[ht][rt][0] + bv[ht].x, 0.f) * gw[rt];
                    float v1 = fmaxf(acc[ht][rt][1] + bv[ht].y, 0.f) * gw[rt];
                    float v2 = fmaxf(acc[ht][rt][2] + bv[ht].z, 0.f) * gw[rt];
                    float v3 = fmaxf(acc[ht][rt][3] + bv[ht].w, 0.f) * gw[rt];
                    uint2 p;
                    p.x = pack_bf16x2(v0, v1);
                    p.y = pack_bf16x2(v2, v3);
                    *(uint2*)(&h_s[(r << 8) + ((ch ^ (r & 7)) << 3) + off]) = p;
                }
            }
        }

        lds_barrier();   // h_s(e) final, visible to crew1 next phase
    }

    // ---- final store: out^T frags -> out (eg=0) or partial (eg=1) ----
    if (crew == 1) {
        float* po = ((eg == 0) ? out : part1) + (long)row0 * 256;
#pragma unroll
        for (int ot = 0; ot < 4; ++ot)
#pragma unroll
            for (int rt = 0; rt < 8; ++rt)
                *(f32x4*)(po + (long)(rt * 16 + l15) * 256 +
                          g * 64 + ot * 16 + quad * 4) = acc[ot][rt];
    }
}

// ------------------------------ combine ------------------------------------
__global__ __launch_bounds__(256) void combine(const float* __restrict__ p1,
                                               float* __restrict__ out) {
    int i = blockIdx.x * 256 + threadIdx.x;     // 1M float4
    float4 a = ((const float4*)out)[i];
    float4 b = ((const float4*)p1)[i];
    a.x += b.x; a.y += b.y; a.z += b.z; a.w += b.w;
    ((float4*)out)[i] = a;
}

// ------------------------------- launch ------------------------------------
extern "C" void kernel_launch(void* const* d_in, const int* in_sizes, int n_in,
                              void* d_out, int out_size, void* d_ws, size_t ws_size,
                              hipStream_t stream) {
    (void)in_sizes; (void)n_in; (void)out_size; (void)ws_size;
    const float* x  = (const float*)d_in[0];   // [16384,256]
    const float* W1 = (const float*)d_in[1];   // [32,256,256]
    const float* b1 = (const float*)d_in[2];   // [32,256]
    const float* W2 = (const float*)d_in[3];   // [32,256,256]
    const float* b2 = (const float*)d_in[4];   // [32,256]
    const float* Wg = (const float*)d_in[5];   // [32,256]
    const float* bg = (const float*)d_in[6];   // [32]
    float* out = (float*)d_out;                // [16384,256]

    // ws: Wr (32 experts + prefetch-overrun pad) at 0; part1 16 MB at 16 MB.
    unsigned short* Wr    = (unsigned short*)d_ws;
    float*          part1 = (float*)((char*)d_ws + (16u << 20));

    cvt_w<<<2048, 256, 0, stream>>>(W1, W2, Wr);
    moe_kernel<<<256, 512, 0, stream>>>(x, Wr, b1, b2, Wg, bg, out, part1);
    combine<<<4096, 256, 0, stream>>>(part1, out);
}